// Round 7
// baseline (285.725 us; speedup 1.0000x reference)
//
#include <hip/hip_runtime.h>

#define KCODES 512
#define DIM 64
#define NB 32
#define NH 64
#define NW 64
#define NPTS (NB*NH*NW)     // 131072
#define HW (NH*NW)          // 4096

// ---- output layout (floats) ----
#define O_OUT  0
#define O_LOSS 8388608
#define O_IDX  8388609
#define O_EMB  8519681
#define O_M    8552449
#define O_MM   8585217

// ---- workspace layout (floats) ----
#define W_DM   0
#define W_CNT  (KCODES*DIM)
#define W_LOSS (W_CNT + KCODES)
#define W_C    (W_LOSS + 1)
#define W_NEWM (W_C + KCODES)
#define W_TOTAL (W_NEWM + KCODES)

#define XPAD 68
#define EPAD 68

__global__ void cnorm_kernel(const float* __restrict__ emb, float* __restrict__ ws) {
    int k = blockIdx.x * blockDim.x + threadIdx.x;
    if (k >= KCODES) return;
    float s = 0.f;
    #pragma unroll
    for (int d = 0; d < DIM; ++d) { float v = emb[k*DIM + d]; s += v*v; }
    ws[W_C + k] = s;
}

// Register-tiled fp32 GEMM (128 pts x 512 cw per block, 8x8 microtile).
// vs r6: (1) X staged via 4 coalesced b32 loads + one ds_write_b128
// (r6's 4x b32 scatter-writes were 8-way bank conflicts: 2.49M cycles);
// (2) loss = best_score + |x|^2 (identity) -> epilogue XL re-reads deleted;
// (3) E-tile global->reg prefetch so HBM/L2 latency hides under the c-loop.
__global__ __launch_bounds__(256, 2) void assign_kernel(
    const float* __restrict__ enc, const float* __restrict__ emb,
    float* __restrict__ out, float* __restrict__ ws)
{
    __shared__ float XL[128*XPAD];   // [point][d]
    __shared__ float EL[128*EPAD];   // [cw][d], aliased as T2 in epilogue
    __shared__ float cnT[128];
    __shared__ int   bestI[128];
    __shared__ float xxL[128];       // per-point |x|^2

    const int t  = threadIdx.x;
    const int tx = t & 15;
    const int ty = t >> 4;
    const int wv = t >> 6, w = t & 63;
    const int R0 = blockIdx.x * 2;

    if (t < 128) xxL[t] = 0.f;
    __syncthreads();

    // ---- stage X: thread = (point w, dim-quad q4); 4 coalesced b32 loads,
    // one b128 LDS write (bank-quad = (p+q4) mod 8: conflict-free) ----
    #pragma unroll
    for (int r2 = 0; r2 < 2; ++r2) {
        int R = R0 + r2, b = R >> 6, h = R & 63;
        const float* base = enc + (size_t)b*64*HW + (size_t)h*64 + w;
        int p = r2*64 + w;
        #pragma unroll
        for (int it = 0; it < 4; ++it) {
            int q4 = it*4 + wv;
            int d0 = q4*4;
            float4 v = make_float4(base[(size_t)(d0+0)*HW], base[(size_t)(d0+1)*HW],
                                   base[(size_t)(d0+2)*HW], base[(size_t)(d0+3)*HW]);
            *(float4*)(&XL[p*XPAD + d0]) = v;
            atomicAdd(&xxL[p], v.x*v.x + v.y*v.y + v.z*v.z + v.w*v.w);
        }
    }

    // ---- prefetch E tile 0 into registers ----
    float4 pre[8];
    {
        const float* esrc = emb;
        #pragma unroll
        for (int it = 0; it < 8; ++it) {
            int idx = t + it*256;
            pre[it] = *(const float4*)(esrc + (idx >> 4)*64 + (idx & 15)*4);
        }
    }

    float best[8]; int bidx[8];
    #pragma unroll
    for (int i = 0; i < 8; ++i) { best[i] = 3.402823466e38f; bidx[i] = 0; }

    for (int tile = 0; tile < 4; ++tile) {
        __syncthreads();             // prior tile's EL reads done
        #pragma unroll
        for (int it = 0; it < 8; ++it) {
            int idx = t + it*256;
            *(float4*)(&EL[(idx >> 4)*EPAD + (idx & 15)*4]) = pre[it];
        }
        if (t < 128) cnT[t] = ws[W_C + tile*128 + t];
        if (tile < 3) {              // issue next-tile loads; latency hides
            const float* esrc = emb + (size_t)(tile+1)*128*64;   // under c-loop
            #pragma unroll
            for (int it = 0; it < 8; ++it) {
                int idx = t + it*256;
                pre[it] = *(const float4*)(esrc + (idx >> 4)*64 + (idx & 15)*4);
            }
        }
        __syncthreads();

        float acc[8][8];
        #pragma unroll
        for (int i = 0; i < 8; ++i)
            #pragma unroll
            for (int j = 0; j < 8; ++j) acc[i][j] = 0.f;

        for (int c = 0; c < 16; ++c) {
            float4 xf[8], ef[8];
            #pragma unroll
            for (int i = 0; i < 8; ++i) {    // 16-lane broadcast reads
                int p = 2*ty + (i&1) + 32*(i>>1);
                xf[i] = *(const float4*)(&XL[p*XPAD + c*4]);
            }
            #pragma unroll
            for (int j = 0; j < 8; ++j) {    // 16 rows -> 2 addrs/quad = floor
                int r = tx + 16*j;
                ef[j] = *(const float4*)(&EL[r*EPAD + c*4]);
            }
            #pragma unroll
            for (int i = 0; i < 8; ++i)
                #pragma unroll
                for (int j = 0; j < 8; ++j) {
                    acc[i][j] = fmaf(xf[i].x, ef[j].x, acc[i][j]);
                    acc[i][j] = fmaf(xf[i].y, ef[j].y, acc[i][j]);
                    acc[i][j] = fmaf(xf[i].z, ef[j].z, acc[i][j]);
                    acc[i][j] = fmaf(xf[i].w, ef[j].w, acc[i][j]);
                }
        }

        #pragma unroll
        for (int j = 0; j < 8; ++j) {
            int k = tile*128 + tx + 16*j;
            float cn = cnT[tx + 16*j];
            #pragma unroll
            for (int i = 0; i < 8; ++i) {
                float s = cn - 2.f*acc[i][j];
                if (s < best[i] || (s == best[i] && k < bidx[i])) { best[i] = s; bidx[i] = k; }
            }
        }
    }

    // ---- cross-lane argmin + loss via |x-q|^2 = best + |x|^2 ----
    float lsum = 0.f;
    #pragma unroll
    for (int i = 0; i < 8; ++i) {
        float b = best[i]; int kx = bidx[i];
        #pragma unroll
        for (int off = 1; off < 16; off <<= 1) {
            float ob = __shfl_xor(b, off, 64);
            int   ok = __shfl_xor(kx, off, 64);
            if (ob < b || (ob == b && ok < kx)) { b = ob; kx = ok; }
        }
        int p = 2*ty + (i&1) + 32*(i>>1);
        if (tx == 0) { bestI[p] = kx; lsum += b + xxL[p]; }
    }
    __syncthreads();

    if (t < 128) out[O_IDX + (size_t)R0*64 + t] = (float)bestI[t];

    // ---- epilogue: quantized gather via wave tile (T2 aliases EL) ----
    float (*T2)[64][17] = (float(*)[64][17])EL;
    const int row = wv & 1, dhalf = wv >> 1;
    const int pg = w >> 4, dl = w & 15;
    const int R = R0 + row, bb = R >> 6, hh = R & 63;
    float* po = out + O_OUT + ((size_t)bb*64)*HW + (size_t)hh*64 + w;

    #pragma unroll
    for (int c2 = 0; c2 < 2; ++c2) {
        int c = dhalf*2 + c2;
        #pragma unroll
        for (int jj = 0; jj < 16; ++jj) {
            int p16 = jj*4 + pg;
            int kb = bestI[row*64 + p16];
            T2[wv][p16][dl] = emb[kb*64 + c*16 + dl];
        }
        #pragma unroll
        for (int i = 0; i < 16; ++i)
            po[(size_t)(c*16 + i)*HW] = T2[wv][w][i];
    }

    #pragma unroll
    for (int off = 32; off >= 1; off >>= 1) lsum += __shfl_down(lsum, off, 64);
    if (w == 0) atomicAdd(&ws[W_LOSS], lsum);
}

// 256 blocks (1/CU), 512 points each: per-block LDS dm/cnt accumulation,
// one coalesced 64-lane global atomic per nonzero codeword row.
__global__ __launch_bounds__(256, 1) void scatter_kernel(
    const float* __restrict__ enc, const float* __restrict__ out,
    float* __restrict__ ws)
{
    __shared__ float dmL[KCODES][65];
    __shared__ float cntL[KCODES];
    __shared__ float T[4][64][17];
    const int t = threadIdx.x;
    const int w = t & 63;
    const int wv = t >> 6;
    const int pg = w >> 4, dl = w & 15;

    float* dmf = &dmL[0][0];
    for (int i = t; i < KCODES*65; i += 256) dmf[i] = 0.f;
    for (int i = t; i < KCODES; i += 256) cntL[i] = 0.f;
    __syncthreads();

    for (int r = 0; r < 2; ++r) {
        const int R = blockIdx.x * 8 + r*4 + wv;
        const int b = R >> 6, h = R & 63;
        const float* px = enc + (size_t)b * DIM * HW + (size_t)h * NW + w;
        int bidx = (int)out[O_IDX + (size_t)R*64 + w];
        atomicAdd(&cntL[bidx], 1.0f);

        #pragma unroll
        for (int c = 0; c < 4; ++c) {
            #pragma unroll
            for (int i = 0; i < 16; ++i)
                T[wv][w][i] = px[(size_t)(c*16 + i) * HW];   // coalesced
            #pragma unroll
            for (int jj = 0; jj < 16; ++jj) {   // same-codeword lanes hit
                int p = jj*4 + pg;              // DIFFERENT dims
                int kb = __shfl(bidx, p, 64);
                atomicAdd(&dmL[kb][c*16 + dl], T[wv][p][dl]);
            }
        }
    }
    __syncthreads();

    for (int k = wv*128; k < wv*128 + 128; ++k) {
        float c = cntL[k];
        if (c == 0.f) continue;
        atomicAdd(&ws[W_DM + k*64 + w], dmL[k][w]);
        if (w == 0) atomicAdd(&ws[W_CNT + k], c);
    }
}

__global__ void finalizeA(const float* __restrict__ emaM,
                          float* __restrict__ out, float* __restrict__ ws)
{
    __shared__ float red[512];
    int k = threadIdx.x;
    float nM = 0.99f * emaM[k] + 0.01f * ws[W_CNT + k];
    red[k] = nM;
    __syncthreads();
    for (int s = 256; s >= 1; s >>= 1) {
        if (k < s) red[k] += red[k + s];
        __syncthreads();
    }
    float Ntot = red[0];
    float sm = (nM + 1e-5f) / (Ntot + 1e-5f * (float)KCODES) * Ntot;
    ws[W_NEWM + k] = sm;
    out[O_MM + k] = sm;
    if (k == 0) out[O_LOSS] = 0.25f * ws[W_LOSS] / (float)((size_t)NPTS * DIM);
}

__global__ void finalizeB(const float* __restrict__ emam,
                          float* __restrict__ out, const float* __restrict__ ws)
{
    int i = blockIdx.x * blockDim.x + threadIdx.x;
    int k = i >> 6;
    float nm = 0.99f * emam[i] + 0.01f * ws[W_DM + i];
    out[O_M + i] = nm;
    out[O_EMB + i] = nm / ws[W_NEWM + k];
}

extern "C" void kernel_launch(void* const* d_in, const int* in_sizes, int n_in,
                              void* d_out, int out_size, void* d_ws, size_t ws_size,
                              hipStream_t stream)
{
    const float* enc  = (const float*)d_in[0];
    const float* emb  = (const float*)d_in[1];
    const float* emam = (const float*)d_in[2];
    const float* emaM = (const float*)d_in[3];
    float* out = (float*)d_out;
    float* ws  = (float*)d_ws;

    hipMemsetAsync(ws, 0, (size_t)W_TOTAL * sizeof(float), stream);
    cnorm_kernel<<<2, 256, 0, stream>>>(emb, ws);
    assign_kernel<<<NPTS/128, 256, 0, stream>>>(enc, emb, out, ws);   // 1024 blocks
    scatter_kernel<<<256, 256, 0, stream>>>(enc, out, ws);
    finalizeA<<<1, 512, 0, stream>>>(emaM, out, ws);
    finalizeB<<<(KCODES*DIM)/256, 256, 0, stream>>>(emam, out, ws);
}